// Round 10
// baseline (277.622 us; speedup 1.0000x reference)
//
#include <hip/hip_runtime.h>
#include <stdint.h>

#define B_ 128
#define N_ 512
#define I_ 256
#define M_ 32
#define D_ 16

typedef __attribute__((ext_vector_type(4))) float f32x4;
typedef __attribute__((ext_vector_type(4))) float float4v;
typedef __attribute__((ext_vector_type(8))) short short8;     // 8 bf16 MFMA frag
typedef __attribute__((ext_vector_type(4))) unsigned int u32x4;
typedef __attribute__((ext_vector_type(4))) unsigned short ushort4v;
typedef unsigned short ushort;

__device__ __forceinline__ float bf2f(ushort u) {
    union { unsigned int i; float f; } v; v.i = ((unsigned int)u) << 16; return v.f;
}
__device__ __forceinline__ ushort f2bf(float f) {
    union { float f; unsigned int i; } v; v.f = f;
    unsigned int r = v.i + 0x7FFFu + ((v.i >> 16) & 1u);   // RNE
    return (ushort)(r >> 16);
}

__device__ __forceinline__ short8 cvt8(float4v lo, float4v hi) {
    unsigned int u0, u1, u2, u3;
    asm("v_cvt_pk_bf16_f32 %0, %1, %2" : "=v"(u0) : "v"(lo[0]), "v"(lo[1]));
    asm("v_cvt_pk_bf16_f32 %0, %1, %2" : "=v"(u1) : "v"(lo[2]), "v"(lo[3]));
    asm("v_cvt_pk_bf16_f32 %0, %1, %2" : "=v"(u2) : "v"(hi[0]), "v"(hi[1]));
    asm("v_cvt_pk_bf16_f32 %0, %1, %2" : "=v"(u3) : "v"(hi[2]), "v"(hi[3]));
    u32x4 uv = {u0, u1, u2, u3};
    return __builtin_bit_cast(short8, uv);
}

// volatile asm 16B load with compile-time byte offset; cannot be sunk/split.
#define GL16(dst, base, imm) \
    asm volatile("global_load_dwordx4 %0, %1, off offset:%2" \
                 : "=&v"(dst) : "v"(base), "n"(imm))

#define VM10() do { \
    asm volatile("s_waitcnt vmcnt(10)" ::: "memory"); \
    __builtin_amdgcn_sched_barrier(0); \
} while (0)

#define VM0() do { \
    asm volatile("s_waitcnt vmcnt(0)" ::: "memory"); \
    __builtin_amdgcn_sched_barrier(0); \
} while (0)

// -----------------------------------------------------------------------------
// Kernel 0: x[b][n][i] fp32 -> xT[n][b][i] bf16.  Pure streaming.
// -----------------------------------------------------------------------------
__global__ __launch_bounds__(256) void conv_x(const float* __restrict__ x,
                                              ushort* __restrict__ xT) {
    const int rid = blockIdx.x * 4 + (threadIdx.x >> 6);   // rid = b*512 + n
    const int i0  = (threadIdx.x & 63) * 4;
    const int b   = rid >> 9;
    const int n   = rid & 511;
    float4v v = *(const float4v*)(x + (size_t)rid * I_ + i0);
    ushort4v h;
    h[0] = f2bf(v[0]); h[1] = f2bf(v[1]); h[2] = f2bf(v[2]); h[3] = f2bf(v[3]);
    *(ushort4v*)(xT + ((size_t)(n * B_ + b)) * I_ + i0) = h;
}

// -----------------------------------------------------------------------------
// Kernel 1: inputs_hat[b,m,n,d] = sum_i x[b,n,i] * W[m,n,d,i]
// One WAVE per (m,n): no LDS, no barriers, no vmcnt(0) drain in the loop.
// Per K-step (32 k's): 10 volatile-asm loads (8 A short8 from xT bf16 via
// offset imm, 2 B float4 from W) double-buffered; s_waitcnt vmcnt(10) waits
// only the PREVIOUS step's loads -> every wave keeps 10-20 loads in flight
// for its whole life (r7/8/9 all drained to 0 per tile = the shared 151us).
// XCD-chunked tasks: blocks round-robin XCDs (blk&7), each XCD gets a
// contiguous n-range so its xT slices live in its private L2.
// -----------------------------------------------------------------------------
__global__ __launch_bounds__(256, 3) void hat_gemm(const float* __restrict__ W,
                                                   const ushort* __restrict__ xT,
                                                   ushort* __restrict__ hat) {
    const int blk = blockIdx.x;               // 0..4095
    const int wv  = threadIdx.x >> 6;         // 0..3
    const int t   = (blk & 7) * 2048 + (blk >> 3) * 4 + wv;   // task 0..16383
    const int n   = t >> 5;
    const int m   = t & 31;

    const int lane = threadIdx.x & 63;
    const int l15  = lane & 15;
    const int kq   = lane >> 4;               // 0..3

    // A: lane covers b-rows (a*16 + l15), k = kq*8 + j (+ks*32)
    const ushort* ab = xT + ((size_t)n * B_ + l15) * I_ + kq * 8;
    const ushort* ap[8];
    #pragma unroll
    for (int a = 0; a < 8; ++a) ap[a] = ab + (size_t)a * 16 * I_;
    // B: lane covers d-row l15, k = kq*8 + j (+ks*32), fp32
    const float* wb = W + (((size_t)m * N_ + n) * D_ + l15) * I_ + kq * 8;

    f32x4 acc[8];
    #pragma unroll
    for (int a = 0; a < 8; ++a) { f32x4 z = {0.f, 0.f, 0.f, 0.f}; acc[a] = z; }

    short8 A0[8], A1[8];
    float4v B0l, B0h, B1l, B1h;

    #define ISSUE(AA, BL, BH, ks) do { \
        _Pragma("unroll") \
        for (int a = 0; a < 8; ++a) GL16(AA[a], ap[a], (ks) * 64); \
        GL16(BL, wb, (ks) * 128); \
        GL16(BH, wb, (ks) * 128 + 16); \
    } while (0)

    #define COMPUTE(AA, BL, BH) do { \
        short8 bb = cvt8(BL, BH); \
        _Pragma("unroll") \
        for (int a = 0; a < 8; ++a) \
            acc[a] = __builtin_amdgcn_mfma_f32_16x16x32_bf16(AA[a], bb, acc[a], 0, 0, 0); \
    } while (0)

    ISSUE(A0, B0l, B0h, 0);
    ISSUE(A1, B1l, B1h, 1); VM10(); COMPUTE(A0, B0l, B0h);   // s0
    ISSUE(A0, B0l, B0h, 2); VM10(); COMPUTE(A1, B1l, B1h);   // s1
    ISSUE(A1, B1l, B1h, 3); VM10(); COMPUTE(A0, B0l, B0h);   // s2
    ISSUE(A0, B0l, B0h, 4); VM10(); COMPUTE(A1, B1l, B1h);   // s3
    ISSUE(A1, B1l, B1h, 5); VM10(); COMPUTE(A0, B0l, B0h);   // s4
    ISSUE(A0, B0l, B0h, 6); VM10(); COMPUTE(A1, B1l, B1h);   // s5
    ISSUE(A1, B1l, B1h, 7); VM10(); COMPUTE(A0, B0l, B0h);   // s6
    VM0();                          COMPUTE(A1, B1l, B1h);   // s7

    #undef ISSUE
    #undef COMPUTE

    // epilogue: D map col = lane&15, row = (lane>>4)*4 + r (verified)
    #pragma unroll
    for (int a = 0; a < 8; ++a) {
        #pragma unroll
        for (int r = 0; r < 4; ++r) {
            const int brow = a * 16 + kq * 4 + r;
            const size_t idx = (((size_t)brow * M_ + m) * N_ + n) * D_ + l15;
            hat[idx] = f2bf(acc[a][r]);
        }
    }
}

// -----------------------------------------------------------------------------
// Kernel 2: dynamic routing (3 iterations), one block per batch element b.
// (unchanged — known-correct)
// -----------------------------------------------------------------------------
__global__ __launch_bounds__(512) void routing(const ushort* __restrict__ hat,
                                               float* __restrict__ out) {
    __shared__ float blog[M_][N_];
    __shared__ float cmax[N_];
    __shared__ float rcsum[N_];

    const int b    = blockIdx.x;
    const int tid  = threadIdx.x;
    const int lane = tid & 63;
    const int w    = tid >> 6;

    #pragma unroll
    for (int m = 0; m < M_; ++m) blog[m][tid] = 0.f;
    __syncthreads();

    float ov[4][16];

    for (int it = 0; it < 3; ++it) {
        {
            float mx = -3.4e38f;
            #pragma unroll
            for (int m = 0; m < M_; ++m) mx = fmaxf(mx, blog[m][tid]);
            float s = 0.f;
            #pragma unroll
            for (int m = 0; m < M_; ++m) s += __expf(blog[m][tid] - mx);
            cmax[tid]  = mx;
            rcsum[tid] = 1.f / s;
        }
        __syncthreads();

        float sacc[4][16];
        #pragma unroll
        for (int q = 0; q < 4; ++q)
            #pragma unroll
            for (int dd = 0; dd < 16; ++dd) sacc[q][dd] = 0.f;

        for (int r = 0; r < 8; ++r) {
            const int nn = r * 64 + lane;
            #pragma unroll
            for (int q = 0; q < 4; ++q) {
                const int m = w * 4 + q;
                const float cm = __expf(blog[m][nn] - cmax[nn]) * rcsum[nn];
                const size_t base = (((size_t)b * M_ + m) * N_ + nn) * D_;
                short8 h0 = *(const short8*)(hat + base);
                short8 h1 = *(const short8*)(hat + base + 8);
                #pragma unroll
                for (int dd = 0; dd < 8; ++dd) {
                    sacc[q][dd]     += cm * bf2f((ushort)h0[dd]);
                    sacc[q][8 + dd] += cm * bf2f((ushort)h1[dd]);
                }
            }
        }
        #pragma unroll
        for (int off = 32; off >= 1; off >>= 1) {
            #pragma unroll
            for (int q = 0; q < 4; ++q)
                #pragma unroll
                for (int dd = 0; dd < 16; ++dd)
                    sacc[q][dd] += __shfl_xor(sacc[q][dd], off, 64);
        }
        #pragma unroll
        for (int q = 0; q < 4; ++q) {
            float s2 = 0.f;
            #pragma unroll
            for (int dd = 0; dd < 16; ++dd) s2 += sacc[q][dd] * sacc[q][dd];
            const float scale = s2 / (1.f + s2) / sqrtf(s2 + 1e-7f);
            #pragma unroll
            for (int dd = 0; dd < 16; ++dd) ov[q][dd] = scale * sacc[q][dd];
        }

        if (it < 2) {
            for (int r = 0; r < 8; ++r) {
                const int nn = r * 64 + lane;
                #pragma unroll
                for (int q = 0; q < 4; ++q) {
                    const int m = w * 4 + q;
                    const size_t base = (((size_t)b * M_ + m) * N_ + nn) * D_;
                    short8 h0 = *(const short8*)(hat + base);
                    short8 h1 = *(const short8*)(hat + base + 8);
                    float dot = 0.f;
                    #pragma unroll
                    for (int dd = 0; dd < 8; ++dd) {
                        dot += ov[q][dd]     * bf2f((ushort)h0[dd]);
                        dot += ov[q][8 + dd] * bf2f((ushort)h1[dd]);
                    }
                    blog[m][nn] += dot;
                }
            }
        }
        __syncthreads();
    }

    if (lane == 0) {
        #pragma unroll
        for (int q = 0; q < 4; ++q) {
            const int m = w * 4 + q;
            #pragma unroll
            for (int c4 = 0; c4 < 4; ++c4) {
                float4v v;
                v[0] = ov[q][c4 * 4 + 0];
                v[1] = ov[q][c4 * 4 + 1];
                v[2] = ov[q][c4 * 4 + 2];
                v[3] = ov[q][c4 * 4 + 3];
                *(float4v*)&out[((size_t)b * M_ + m) * D_ + c4 * 4] = v;
            }
        }
    }
}

extern "C" void kernel_launch(void* const* d_in, const int* in_sizes, int n_in,
                              void* d_out, int out_size, void* d_ws, size_t ws_size,
                              hipStream_t stream) {
    const float* x = (const float*)d_in[0];        // [128, 512, 256] fp32
    const float* W = (const float*)d_in[1];        // [32, 512, 16, 256] fp32
    ushort* hat = (ushort*)d_ws;                   // bf16 [128,32,512,16] = 64 MB
    ushort* xT  = (ushort*)((char*)d_ws + (size_t)64 * 1024 * 1024); // bf16 [512,128,256] = 32 MB
    float* out = (float*)d_out;                    // fp32 [128,32,16]

    conv_x<<<dim3((B_ * N_) / 4), dim3(256), 0, stream>>>(x, xT);
    hat_gemm<<<dim3(4096), dim3(256), 0, stream>>>(W, xT, hat);
    routing<<<dim3(B_), dim3(512), 0, stream>>>(hat, out);
}

// Round 11
// 173.813 us; speedup vs baseline: 1.5972x; 1.5972x over previous
//
#include <hip/hip_runtime.h>
#include <stdint.h>

#define B_ 128
#define N_ 512
#define I_ 256
#define M_ 32
#define D_ 16

typedef __attribute__((ext_vector_type(4))) float f32x4;
typedef __attribute__((ext_vector_type(4))) float float4v;
typedef __attribute__((ext_vector_type(8))) short short8;     // 8 bf16 MFMA frag
typedef __attribute__((ext_vector_type(4))) unsigned int u32x4;
typedef __attribute__((ext_vector_type(4))) unsigned short ushort4v;
typedef unsigned short ushort;

__device__ __forceinline__ float bf2f(ushort u) {
    union { unsigned int i; float f; } v; v.i = ((unsigned int)u) << 16; return v.f;
}
__device__ __forceinline__ ushort f2bf(float f) {
    union { float f; unsigned int i; } v; v.f = f;
    unsigned int r = v.i + 0x7FFFu + ((v.i >> 16) & 1u);   // RNE
    return (ushort)(r >> 16);
}

__device__ __forceinline__ short8 cvt8(float4v lo, float4v hi) {
    unsigned int u0, u1, u2, u3;
    asm("v_cvt_pk_bf16_f32 %0, %1, %2" : "=v"(u0) : "v"(lo[0]), "v"(lo[1]));
    asm("v_cvt_pk_bf16_f32 %0, %1, %2" : "=v"(u1) : "v"(lo[2]), "v"(lo[3]));
    asm("v_cvt_pk_bf16_f32 %0, %1, %2" : "=v"(u2) : "v"(hi[0]), "v"(hi[1]));
    asm("v_cvt_pk_bf16_f32 %0, %1, %2" : "=v"(u3) : "v"(hi[2]), "v"(hi[3]));
    u32x4 uv = {u0, u1, u2, u3};
    return __builtin_bit_cast(short8, uv);
}

// volatile asm 16B load with compile-time byte offset; cannot be sunk/split.
#define GL16(dst, base, imm) \
    asm volatile("global_load_dwordx4 %0, %1, off offset:%2" \
                 : "=&v"(dst) : "v"(base), "n"(imm))

#define VMW(nn) do { \
    asm volatile("s_waitcnt vmcnt(" #nn ")" ::: "memory"); \
    __builtin_amdgcn_sched_barrier(0); \
} while (0)

// -----------------------------------------------------------------------------
// Kernel 1: inputs_hat[b,m,n,d] = sum_i x[b,n,i] * W[m,n,d,i]
// TRAFFIC-MINIMAL structure (r10 lesson: machine was at ~6.6 TB/s on
// REDUNDANT reads). One block per n: x[.][n] staged ONCE to LDS (bf16,
// XOR-swizzled 16B granules), shared by all 32 m's. 8 waves x 4 m's each;
// W[m][n] (16KB contiguous) streamed once via depth-2 counted-vmcnt GL16.
// Ideal bytes: x 64MB + W 256MB + hat 64MB = 384MB ~= 61us floor.
// -----------------------------------------------------------------------------
__global__ __launch_bounds__(512, 4) void hat_gemm(const float* __restrict__ x,
                                                   const float* __restrict__ W,
                                                   ushort* __restrict__ hat) {
    __shared__ ushort As[128 * 256];    // 64 KB; granule g of row r at g^(r&15)

    const int bid = blockIdx.x;         // 0..511
    const int n   = (bid & 7) * 64 + (bid >> 3);   // XCD-chunked n

    const int tid  = threadIdx.x;       // 0..511
    const int lane = tid & 63;
    const int w    = tid >> 6;          // wave 0..7
    const int l15  = lane & 15;
    const int kq   = lane >> 4;         // 0..3

    // ---- stage x[.][n] -> bf16 LDS (one time; 256B per thread) ----
    {
        const int row = tid >> 2;       // b = 0..127
        const int seg = tid & 3;        // 64 floats each
        const float* xp = x + ((size_t)row * N_ + n) * I_ + seg * 64;
        float4v sv[16];
        #pragma unroll
        for (int j = 0; j < 16; ++j) GL16(sv[j], xp, j * 16);
        VMW(0);
        #pragma unroll
        for (int i = 0; i < 8; ++i) {
            short8 h = cvt8(sv[2 * i], sv[2 * i + 1]);
            const int gsw = ((seg * 8 + i) ^ (row & 15));
            *(short8*)&As[row * 256 + gsw * 8] = h;
        }
    }
    __syncthreads();    // the ONLY barrier

    // ---- main: wave w handles m = w*4 + mq, mq = 0..3 sequentially ----
    // A-frag (a,ks): row r = a*16+l15, granule (ks*4+kq)^l15.
    const int abase = l15 * 256;        // + a*4096 + gsw*8

    #pragma unroll
    for (int mq = 0; mq < 4; ++mq) {
        const int m = w * 4 + mq;
        const float* wb = W + (((size_t)m * N_ + n) * D_ + l15) * I_ + kq * 8;

        f32x4 acc[8];
        #pragma unroll
        for (int a = 0; a < 8; ++a) { f32x4 z = {0.f, 0.f, 0.f, 0.f}; acc[a] = z; }

        float4v L0, H0, L1, H1;
        GL16(L0, wb, 0);   GL16(H0, wb, 16);      // ks=0 pair
        GL16(L1, wb, 128); GL16(H1, wb, 144);     // ks=1 pair

        #pragma unroll
        for (int ks = 0; ks < 8; ++ks) {
            if (ks < 7) VMW(2); else VMW(0);      // current pair landed
            short8 bb;
            if ((ks & 1) == 0) bb = cvt8(L0, H0); else bb = cvt8(L1, H1);
            // issue pair ks+2 into the just-freed buffer
            if (ks < 6) {
                const int off = (ks + 2) * 128;
                if ((ks & 1) == 0) { GL16(L0, wb, off); GL16(H0, wb, off + 16); }
                else               { GL16(L1, wb, off); GL16(H1, wb, off + 16); }
            }
            const int gsw = ((ks * 4 + kq) ^ l15) * 8;
            #pragma unroll
            for (int a = 0; a < 8; ++a) {
                short8 af = *(const short8*)&As[abase + a * 4096 + gsw];
                acc[a] = __builtin_amdgcn_mfma_f32_16x16x32_bf16(af, bb, acc[a], 0, 0, 0);
            }
        }

        // epilogue for this m: D map col = lane&15, row = (lane>>4)*4 + r
        #pragma unroll
        for (int a = 0; a < 8; ++a) {
            #pragma unroll
            for (int r = 0; r < 4; ++r) {
                const int brow = a * 16 + kq * 4 + r;
                const size_t idx = (((size_t)brow * M_ + m) * N_ + n) * D_ + l15;
                hat[idx] = f2bf(acc[a][r]);
            }
        }
        // stores sit in the vmcnt FIFO ahead of next m's loads; the next
        // VMW(2) counts them as completed-first (in-order) — no extra drain.
    }
}

// -----------------------------------------------------------------------------
// Kernel 2: dynamic routing (3 iterations), one block per batch element b.
// (unchanged — known-correct)
// -----------------------------------------------------------------------------
__global__ __launch_bounds__(512) void routing(const ushort* __restrict__ hat,
                                               float* __restrict__ out) {
    __shared__ float blog[M_][N_];
    __shared__ float cmax[N_];
    __shared__ float rcsum[N_];

    const int b    = blockIdx.x;
    const int tid  = threadIdx.x;
    const int lane = tid & 63;
    const int w    = tid >> 6;

    #pragma unroll
    for (int m = 0; m < M_; ++m) blog[m][tid] = 0.f;
    __syncthreads();

    float ov[4][16];

    for (int it = 0; it < 3; ++it) {
        {
            float mx = -3.4e38f;
            #pragma unroll
            for (int m = 0; m < M_; ++m) mx = fmaxf(mx, blog[m][tid]);
            float s = 0.f;
            #pragma unroll
            for (int m = 0; m < M_; ++m) s += __expf(blog[m][tid] - mx);
            cmax[tid]  = mx;
            rcsum[tid] = 1.f / s;
        }
        __syncthreads();

        float sacc[4][16];
        #pragma unroll
        for (int q = 0; q < 4; ++q)
            #pragma unroll
            for (int dd = 0; dd < 16; ++dd) sacc[q][dd] = 0.f;

        for (int r = 0; r < 8; ++r) {
            const int nn = r * 64 + lane;
            #pragma unroll
            for (int q = 0; q < 4; ++q) {
                const int m = w * 4 + q;
                const float cm = __expf(blog[m][nn] - cmax[nn]) * rcsum[nn];
                const size_t base = (((size_t)b * M_ + m) * N_ + nn) * D_;
                short8 h0 = *(const short8*)(hat + base);
                short8 h1 = *(const short8*)(hat + base + 8);
                #pragma unroll
                for (int dd = 0; dd < 8; ++dd) {
                    sacc[q][dd]     += cm * bf2f((ushort)h0[dd]);
                    sacc[q][8 + dd] += cm * bf2f((ushort)h1[dd]);
                }
            }
        }
        #pragma unroll
        for (int off = 32; off >= 1; off >>= 1) {
            #pragma unroll
            for (int q = 0; q < 4; ++q)
                #pragma unroll
                for (int dd = 0; dd < 16; ++dd)
                    sacc[q][dd] += __shfl_xor(sacc[q][dd], off, 64);
        }
        #pragma unroll
        for (int q = 0; q < 4; ++q) {
            float s2 = 0.f;
            #pragma unroll
            for (int dd = 0; dd < 16; ++dd) s2 += sacc[q][dd] * sacc[q][dd];
            const float scale = s2 / (1.f + s2) / sqrtf(s2 + 1e-7f);
            #pragma unroll
            for (int dd = 0; dd < 16; ++dd) ov[q][dd] = scale * sacc[q][dd];
        }

        if (it < 2) {
            for (int r = 0; r < 8; ++r) {
                const int nn = r * 64 + lane;
                #pragma unroll
                for (int q = 0; q < 4; ++q) {
                    const int m = w * 4 + q;
                    const size_t base = (((size_t)b * M_ + m) * N_ + nn) * D_;
                    short8 h0 = *(const short8*)(hat + base);
                    short8 h1 = *(const short8*)(hat + base + 8);
                    float dot = 0.f;
                    #pragma unroll
                    for (int dd = 0; dd < 8; ++dd) {
                        dot += ov[q][dd]     * bf2f((ushort)h0[dd]);
                        dot += ov[q][8 + dd] * bf2f((ushort)h1[dd]);
                    }
                    blog[m][nn] += dot;
                }
            }
        }
        __syncthreads();
    }

    if (lane == 0) {
        #pragma unroll
        for (int q = 0; q < 4; ++q) {
            const int m = w * 4 + q;
            #pragma unroll
            for (int c4 = 0; c4 < 4; ++c4) {
                float4v v;
                v[0] = ov[q][c4 * 4 + 0];
                v[1] = ov[q][c4 * 4 + 1];
                v[2] = ov[q][c4 * 4 + 2];
                v[3] = ov[q][c4 * 4 + 3];
                *(float4v*)&out[((size_t)b * M_ + m) * D_ + c4 * 4] = v;
            }
        }
    }
}

extern "C" void kernel_launch(void* const* d_in, const int* in_sizes, int n_in,
                              void* d_out, int out_size, void* d_ws, size_t ws_size,
                              hipStream_t stream) {
    const float* x = (const float*)d_in[0];        // [128, 512, 256] fp32
    const float* W = (const float*)d_in[1];        // [32, 512, 16, 256] fp32
    ushort* hat = (ushort*)d_ws;                   // bf16 [128,32,512,16] = 64 MB
    float* out = (float*)d_out;                    // fp32 [128,32,16]

    hat_gemm<<<dim3(N_), dim3(512), 0, stream>>>(x, W, hat);
    routing<<<dim3(B_), dim3(512), 0, stream>>>(hat, out);
}

// Round 13
// 173.388 us; speedup vs baseline: 1.6012x; 1.0025x over previous
//
#include <hip/hip_runtime.h>
#include <stdint.h>

#define B_ 128
#define N_ 512
#define I_ 256
#define M_ 32
#define D_ 16

typedef __attribute__((ext_vector_type(4))) float f32x4;
typedef __attribute__((ext_vector_type(4))) float float4v;
typedef __attribute__((ext_vector_type(8))) short short8;     // 8 bf16 MFMA frag
typedef __attribute__((ext_vector_type(4))) unsigned int u32x4;
typedef __attribute__((ext_vector_type(4))) unsigned short ushort4v;
typedef unsigned short ushort;

__device__ __forceinline__ float bf2f(ushort u) {
    union { unsigned int i; float f; } v; v.i = ((unsigned int)u) << 16; return v.f;
}
__device__ __forceinline__ ushort f2bf(float f) {
    union { float f; unsigned int i; } v; v.f = f;
    unsigned int r = v.i + 0x7FFFu + ((v.i >> 16) & 1u);   // RNE
    return (ushort)(r >> 16);
}

__device__ __forceinline__ short8 cvt8(float4v lo, float4v hi) {
    unsigned int u0, u1, u2, u3;
    asm("v_cvt_pk_bf16_f32 %0, %1, %2" : "=v"(u0) : "v"(lo[0]), "v"(lo[1]));
    asm("v_cvt_pk_bf16_f32 %0, %1, %2" : "=v"(u1) : "v"(lo[2]), "v"(lo[3]));
    asm("v_cvt_pk_bf16_f32 %0, %1, %2" : "=v"(u2) : "v"(hi[0]), "v"(hi[1]));
    asm("v_cvt_pk_bf16_f32 %0, %1, %2" : "=v"(u3) : "v"(hi[2]), "v"(hi[3]));
    u32x4 uv = {u0, u1, u2, u3};
    return __builtin_bit_cast(short8, uv);
}

// volatile asm 16B load with compile-time byte offset; cannot be sunk/split.
#define GL16(dst, base, imm) \
    asm volatile("global_load_dwordx4 %0, %1, off offset:%2" \
                 : "=&v"(dst) : "v"(base), "n"(imm))

#define VMW(nn) do { \
    asm volatile("s_waitcnt vmcnt(" #nn ")" ::: "memory"); \
    __builtin_amdgcn_sched_barrier(0); \
} while (0)

// -----------------------------------------------------------------------------
// Kernel 1: inputs_hat[b,m,n,d] = sum_i x[b,n,i] * W[m,n,d,i]
// r11 traffic-minimal structure (block per n, x staged once to LDS bf16,
// W streamed exactly once), W pipeline deepened 2 -> 4 groups in flight
// (8 loads/wave steady) within a SINGLE m-stream (acc 32 regs) so total
// pressure ~105 < 128 cap -- r12's dual-stream spilled and corrupted the
// asm-load/vmcnt contract. No vmcnt(0) drains mid-kernel: the first counted
// wait of each m over-counts the previous m's in-order stores (harmless).
// -----------------------------------------------------------------------------
__global__ __launch_bounds__(512, 4) void hat_gemm(const float* __restrict__ x,
                                                   const float* __restrict__ W,
                                                   ushort* __restrict__ hat) {
    __shared__ ushort As[128 * 256];    // 64 KB; granule g of row r at g^(r&15)

    const int bid = blockIdx.x;         // 0..511
    const int n   = (bid & 7) * 64 + (bid >> 3);   // XCD-chunked n

    const int tid  = threadIdx.x;       // 0..511
    const int lane = tid & 63;
    const int w    = tid >> 6;          // wave 0..7
    const int l15  = lane & 15;
    const int kq   = lane >> 4;         // 0..3

    // ---- stage x[.][n] -> bf16 LDS (one time; 256B per thread) ----
    {
        const int row = tid >> 2;       // b = 0..127
        const int seg = tid & 3;        // 64 floats each
        const float* xp = x + ((size_t)row * N_ + n) * I_ + seg * 64;
        float4v sv[16];
        #pragma unroll
        for (int j = 0; j < 16; ++j) GL16(sv[j], xp, j * 16);
        VMW(0);
        #pragma unroll
        for (int i = 0; i < 8; ++i) {
            short8 h = cvt8(sv[2 * i], sv[2 * i + 1]);
            const int gsw = ((seg * 8 + i) ^ (row & 15));
            *(short8*)&As[row * 256 + gsw * 8] = h;
        }
    }
    __syncthreads();    // the ONLY barrier

    const int abase = l15 * 256;        // A-frag: + a*4096 + gsw*8

    // MFMA step for K-slice ks (8 frag rows a), shared helper
    #define MF(bb, ks) do { \
        const int gsw_ = (((ks) * 4 + kq) ^ l15) * 8; \
        _Pragma("unroll") \
        for (int a = 0; a < 8; ++a) { \
            short8 af = *(const short8*)&As[abase + a * 4096 + gsw_]; \
            acc[a] = __builtin_amdgcn_mfma_f32_16x16x32_bf16(af, (bb), acc[a], 0, 0, 0); \
        } \
    } while (0)

    // ---- main: wave w handles m = w*4 + mq, mq = 0..3 sequentially ----
    #pragma unroll
    for (int mq = 0; mq < 4; ++mq) {
        const int m = w * 4 + mq;
        const float* wm = W + (((size_t)m * N_ + n) * D_ + l15) * I_ + kq * 8;

        f32x4 acc[8];
        #pragma unroll
        for (int a = 0; a < 8; ++a) { f32x4 z = {0.f, 0.f, 0.f, 0.f}; acc[a] = z; }

        // 4 groups in flight; group g covers W bytes [g*128, g*128+128) per row
        float4v L0, H0, L1, H1, L2, H2, L3, H3;
        GL16(L0, wm, 0);   GL16(H0, wm, 16);
        GL16(L1, wm, 128); GL16(H1, wm, 144);
        GL16(L2, wm, 256); GL16(H2, wm, 272);
        GL16(L3, wm, 384); GL16(H3, wm, 400);

        // ks=0..3: wait group, reuse its regs for group ks+4
        VMW(6); { short8 bb = cvt8(L0, H0); GL16(L0, wm, 512); GL16(H0, wm, 528); MF(bb, 0); }
        VMW(6); { short8 bb = cvt8(L1, H1); GL16(L1, wm, 640); GL16(H1, wm, 656); MF(bb, 1); }
        VMW(6); { short8 bb = cvt8(L2, H2); GL16(L2, wm, 768); GL16(H2, wm, 784); MF(bb, 2); }
        VMW(6); { short8 bb = cvt8(L3, H3); GL16(L3, wm, 896); GL16(H3, wm, 912); MF(bb, 3); }
        // ks=4..7: tail, counts run down
        VMW(6); { short8 bb = cvt8(L0, H0); MF(bb, 4); }
        VMW(4); { short8 bb = cvt8(L1, H1); MF(bb, 5); }
        VMW(2); { short8 bb = cvt8(L2, H2); MF(bb, 6); }
        VMW(0); { short8 bb = cvt8(L3, H3); MF(bb, 7); }

        // epilogue: D map col = lane&15, row = (lane>>4)*4 + r (verified).
        // Stores stay in the vmcnt FIFO; next m's first VMW(6) over-counts
        // them (in-order completion) -- correct, no explicit drain.
        #pragma unroll
        for (int a = 0; a < 8; ++a) {
            #pragma unroll
            for (int r = 0; r < 4; ++r) {
                const int brow = a * 16 + kq * 4 + r;
                const size_t idx = (((size_t)brow * M_ + m) * N_ + n) * D_ + l15;
                hat[idx] = f2bf(acc[a][r]);
            }
        }
    }
    #undef MF
}

// -----------------------------------------------------------------------------
// Kernel 2: dynamic routing (3 iterations), one block per batch element b.
// (unchanged — known-correct)
// -----------------------------------------------------------------------------
__global__ __launch_bounds__(512) void routing(const ushort* __restrict__ hat,
                                               float* __restrict__ out) {
    __shared__ float blog[M_][N_];
    __shared__ float cmax[N_];
    __shared__ float rcsum[N_];

    const int b    = blockIdx.x;
    const int tid  = threadIdx.x;
    const int lane = tid & 63;
    const int w    = tid >> 6;

    #pragma unroll
    for (int m = 0; m < M_; ++m) blog[m][tid] = 0.f;
    __syncthreads();

    float ov[4][16];

    for (int it = 0; it < 3; ++it) {
        {
            float mx = -3.4e38f;
            #pragma unroll
            for (int m = 0; m < M_; ++m) mx = fmaxf(mx, blog[m][tid]);
            float s = 0.f;
            #pragma unroll
            for (int m = 0; m < M_; ++m) s += __expf(blog[m][tid] - mx);
            cmax[tid]  = mx;
            rcsum[tid] = 1.f / s;
        }
        __syncthreads();

        float sacc[4][16];
        #pragma unroll
        for (int q = 0; q < 4; ++q)
            #pragma unroll
            for (int dd = 0; dd < 16; ++dd) sacc[q][dd] = 0.f;

        for (int r = 0; r < 8; ++r) {
            const int nn = r * 64 + lane;
            #pragma unroll
            for (int q = 0; q < 4; ++q) {
                const int m = w * 4 + q;
                const float cm = __expf(blog[m][nn] - cmax[nn]) * rcsum[nn];
                const size_t base = (((size_t)b * M_ + m) * N_ + nn) * D_;
                short8 h0 = *(const short8*)(hat + base);
                short8 h1 = *(const short8*)(hat + base + 8);
                #pragma unroll
                for (int dd = 0; dd < 8; ++dd) {
                    sacc[q][dd]     += cm * bf2f((ushort)h0[dd]);
                    sacc[q][8 + dd] += cm * bf2f((ushort)h1[dd]);
                }
            }
        }
        #pragma unroll
        for (int off = 32; off >= 1; off >>= 1) {
            #pragma unroll
            for (int q = 0; q < 4; ++q)
                #pragma unroll
                for (int dd = 0; dd < 16; ++dd)
                    sacc[q][dd] += __shfl_xor(sacc[q][dd], off, 64);
        }
        #pragma unroll
        for (int q = 0; q < 4; ++q) {
            float s2 = 0.f;
            #pragma unroll
            for (int dd = 0; dd < 16; ++dd) s2 += sacc[q][dd] * sacc[q][dd];
            const float scale = s2 / (1.f + s2) / sqrtf(s2 + 1e-7f);
            #pragma unroll
            for (int dd = 0; dd < 16; ++dd) ov[q][dd] = scale * sacc[q][dd];
        }

        if (it < 2) {
            for (int r = 0; r < 8; ++r) {
                const int nn = r * 64 + lane;
                #pragma unroll
                for (int q = 0; q < 4; ++q) {
                    const int m = w * 4 + q;
                    const size_t base = (((size_t)b * M_ + m) * N_ + nn) * D_;
                    short8 h0 = *(const short8*)(hat + base);
                    short8 h1 = *(const short8*)(hat + base + 8);
                    float dot = 0.f;
                    #pragma unroll
                    for (int dd = 0; dd < 8; ++dd) {
                        dot += ov[q][dd]     * bf2f((ushort)h0[dd]);
                        dot += ov[q][8 + dd] * bf2f((ushort)h1[dd]);
                    }
                    blog[m][nn] += dot;
                }
            }
        }
        __syncthreads();
    }

    if (lane == 0) {
        #pragma unroll
        for (int q = 0; q < 4; ++q) {
            const int m = w * 4 + q;
            #pragma unroll
            for (int c4 = 0; c4 < 4; ++c4) {
                float4v v;
                v[0] = ov[q][c4 * 4 + 0];
                v[1] = ov[q][c4 * 4 + 1];
                v[2] = ov[q][c4 * 4 + 2];
                v[3] = ov[q][c4 * 4 + 3];
                *(float4v*)&out[((size_t)b * M_ + m) * D_ + c4 * 4] = v;
            }
        }
    }
}

extern "C" void kernel_launch(void* const* d_in, const int* in_sizes, int n_in,
                              void* d_out, int out_size, void* d_ws, size_t ws_size,
                              hipStream_t stream) {
    const float* x = (const float*)d_in[0];        // [128, 512, 256] fp32
    const float* W = (const float*)d_in[1];        // [32, 512, 16, 256] fp32
    ushort* hat = (ushort*)d_ws;                   // bf16 [128,32,512,16] = 64 MB
    float* out = (float*)d_out;                    // fp32 [128,32,16]

    hat_gemm<<<dim3(N_), dim3(512), 0, stream>>>(x, W, hat);
    routing<<<dim3(B_), dim3(512), 0, stream>>>(hat, out);
}